// Round 5
// baseline (1017.701 us; speedup 1.0000x reference)
//
#include <hip/hip_runtime.h>
#include <hip/hip_bf16.h>

#define N_ATOMS   500000
#define N_BONDS   1000000
#define MAX_NB    6
#define ATOM_FDIM 133
#define BOND_FDIM 14
#define HIDDEN    128
#define N_MOLS    25000
#define APM       20

typedef __attribute__((ext_vector_type(8))) short short8;
typedef __attribute__((ext_vector_type(4))) float f32x4;
typedef unsigned short u16;
typedef unsigned int   u32;

__device__ __forceinline__ float bf2f(u16 u) {
    u32 t = ((u32)u) << 16;
    return __builtin_bit_cast(float, t);
}
__device__ __forceinline__ u16 f2bf(float f) {
    u32 t = __builtin_bit_cast(u32, f);
    t += 0x7FFFu + ((t >> 16) & 1u);
    return (u16)(t >> 16);
}

// ---------------- weight prep: fp32 -> padded bf16 ----------------
__global__ void prep_weights(const float* __restrict__ Wi, const float* __restrict__ Wh,
                             const float* __restrict__ Wo,
                             u16* __restrict__ Wip, u16* __restrict__ Whp, u16* __restrict__ Wop) {
    int stride = gridDim.x * blockDim.x;
    int tid = blockIdx.x * blockDim.x + threadIdx.x;
    for (int i = tid; i < 128 * 160; i += stride) {
        int r = i / 160, c = i % 160;
        Wip[i] = (c < 133) ? f2bf(Wi[r * 133 + c]) : (u16)0;
        Whp[i] = (c < 142) ? f2bf(Wh[r * 142 + c]) : (u16)0;
    }
    for (int i = tid; i < 128 * 288; i += stride) {
        int r = i / 288, c = i % 288;
        float v = 0.f;
        if (c < 133)      v = Wo[r * 261 + c];
        else if (c >= 160) v = Wo[r * 261 + (c - 27)];
        Wop[i] = f2bf(v);
    }
}

// ---------------- f_atoms fp32 [N][133] -> bf16 [N][160], LDS-staged ----------------
#define CROWS 24
__global__ __launch_bounds__(256) void fa_convert(const float* __restrict__ fa, u16* __restrict__ out) {
    __shared__ float buf[CROWS * 133];
    const long row0 = (long)blockIdx.x * CROWS;
    const int rows = (int)((N_ATOMS - row0) < CROWS ? (N_ATOMS - row0) : CROWS);
    const float* src = fa + row0 * ATOM_FDIM;
    if (rows == CROWS) {
        for (int i = threadIdx.x; i < (CROWS * 133) / 4; i += 256)
            *(float4*)(&buf[i * 4]) = *(const float4*)(src + i * 4);
    } else {
        for (int i = threadIdx.x; i < rows * 133; i += 256) buf[i] = src[i];
    }
    __syncthreads();
    for (int j = threadIdx.x; j < rows * 20; j += 256) {
        int r = j / 20, c8 = (j % 20) * 8;
        u16 u[8];
#pragma unroll
        for (int e = 0; e < 8; e++) {
            int c = c8 + e;
            u[e] = (c < ATOM_FDIM) ? f2bf(buf[r * 133 + c]) : (u16)0;
        }
        uint4 v;
        v.x = (u32)u[0] | ((u32)u[1] << 16);
        v.y = (u32)u[2] | ((u32)u[3] << 16);
        v.z = (u32)u[4] | ((u32)u[5] << 16);
        v.w = (u32)u[6] | ((u32)u[7] << 16);
        *(uint4*)(out + (row0 + r) * 160 + c8) = v;
    }
}

// ---------------- bond pre-sum: sum_j f_bonds[a2b[:,j]] -> bf16 [N][32] ----------------
__global__ __launch_bounds__(256) void bond_gather(const float* __restrict__ fb, const int* __restrict__ a2b,
                                                   u16* __restrict__ outp) {
    long t = (long)blockIdx.x * 256 + threadIdx.x;
    int atom = (int)(t >> 4);
    int c2   = (int)(t & 15);
    if (atom >= N_ATOMS) return;
    int c0 = 2 * c2, c1 = c0 + 1;
    float s0 = 0.f, s1 = 0.f;
    if (c0 < BOND_FDIM) {
#pragma unroll
        for (int j = 0; j < MAX_NB; j++) {
            int idx = a2b[atom * 6 + j];
            const float* row = fb + (long)idx * BOND_FDIM;
            s0 += row[c0];
            if (c1 < BOND_FDIM) s1 += row[c1];
        }
    }
    *(u32*)(outp + (long)atom * 32 + c0) = (u32)f2bf(s0) | ((u32)f2bf(s1) << 16);
}

// ---------------- gather-relu-sum: dst[a] = sum_j relu(src[a2a[a,j]]) (bf16 128-wide) ---
// Standalone: keeps the 128 MB message pool L3-resident with no competing streams.
__global__ __launch_bounds__(256) void gather_relu_sum(const u16* __restrict__ src,
                                                       const int* __restrict__ a2a,
                                                       u16* __restrict__ dst) {
    long t = (long)blockIdx.x * 256 + threadIdx.x;
    int atom = (int)(t >> 4);
    int c8   = (int)(t & 15) << 3;
    float s[8] = {0, 0, 0, 0, 0, 0, 0, 0};
#pragma unroll
    for (int j = 0; j < MAX_NB; j++) {
        int idx = a2a[atom * 6 + j];
        uint4 v = *(const uint4*)(src + (long)idx * 128 + c8);
        u32 w[4] = {v.x, v.y, v.z, v.w};
#pragma unroll
        for (int q = 0; q < 4; q++) {
            s[2 * q]     += fmaxf(__builtin_bit_cast(float, w[q] << 16), 0.f);
            s[2 * q + 1] += fmaxf(__builtin_bit_cast(float, w[q] & 0xFFFF0000u), 0.f);
        }
    }
    uint4 o;
    o.x = (u32)f2bf(s[0]) | ((u32)f2bf(s[1]) << 16);
    o.y = (u32)f2bf(s[2]) | ((u32)f2bf(s[3]) << 16);
    o.z = (u32)f2bf(s[4]) | ((u32)f2bf(s[5]) << 16);
    o.w = (u32)f2bf(s[6]) | ((u32)f2bf(s[7]) << 16);
    *(uint4*)(dst + (long)atom * 128 + c8) = o;
}

// ---------------- N-split GEMM: block computes rows [mblk*128,+128) x cols [nh*64,+64)
// Out = concat(A0,A1)[N][32*KB] @ Wp^T + bias (+Xadd), swapped-operand MFMA:
// D[ocol][atom]; lane atom=(lane&15), ocols=nh*64+n*16+(lane>>4)*4+{0..3} -> 8B stores.
// LDS: 64 rows of W, pad-free flat layout (linear coalesced staging; b128 reads
// spread evenly over all 32 banks). 16 waves/CU via __launch_bounds__(256,4).
template <int KB0, int KB1, bool ADDX>
__global__ __launch_bounds__(256, 4) void gemm_mp(
    const u16* __restrict__ A0, int ldA0,
    const u16* __restrict__ A1, int ldA1,
    const u16* __restrict__ Wp, const float* __restrict__ bias,
    const u16* __restrict__ Xadd, u16* __restrict__ Out) {
    constexpr int KB = KB0 + KB1;
    constexpr int KP = KB * 32;
    __shared__ u16 ldsw[64 * KP];

    const int nh   = blockIdx.x & 1;
    const int mblk = blockIdx.x >> 1;
    const int lane = threadIdx.x & 63;
    const int wave = threadIdx.x >> 6;
    const int lrow = lane & 15;
    const int kg   = lane >> 4;
    const long rowbase = (long)mblk * 128 + wave * 32;

    long ar[2];
#pragma unroll
    for (int m = 0; m < 2; m++) {
        long r = rowbase + m * 16 + lrow;
        if (r >= N_ATOMS) r = N_ATOMS - 1;  // clamp (stores guarded)
        ar[m] = r;
    }

    // ---- hoist all A loads (issue first; stay in flight through staging) ----
    uint4 a0v[2][KB0 ? KB0 : 1];
    uint4 a1v[2][KB1 ? KB1 : 1];
#pragma unroll
    for (int m = 0; m < 2; m++) {
        if constexpr (KB0 > 0) {
            const u16* p0 = A0 + ar[m] * ldA0 + kg * 8;
#pragma unroll
            for (int kb = 0; kb < KB0; kb++) a0v[m][kb] = *(const uint4*)(p0 + kb * 32);
        }
        if constexpr (KB1 > 0) {
            const u16* p1 = A1 + ar[m] * ldA1 + kg * 8;
#pragma unroll
            for (int kb = 0; kb < KB1; kb++) a1v[m][kb] = *(const uint4*)(p1 + kb * 32);
        }
    }

    // ---- stage this block's 64 W rows: flat linear copy (coalesced, no arithmetic) ----
    {
        const u16* wsrc = Wp + (size_t)nh * 64 * KP;
        constexpr int TOT8 = 64 * KP / 8;
        for (int f = threadIdx.x; f < TOT8; f += 256)
            *(uint4*)(&ldsw[f * 8]) = *(const uint4*)(wsrc + f * 8);
    }
    __syncthreads();

    f32x4 acc[2][4];
#pragma unroll
    for (int m = 0; m < 2; m++)
#pragma unroll
        for (int n = 0; n < 4; n++) acc[m][n] = (f32x4){0.f, 0.f, 0.f, 0.f};

#pragma unroll
    for (int kb = 0; kb < KB; kb++) {
        short8 af[2];
#pragma unroll
        for (int m = 0; m < 2; m++) {
            if (kb < KB0) af[m] = __builtin_bit_cast(short8, a0v[m][kb < KB0 ? kb : 0]);
            else          af[m] = __builtin_bit_cast(short8, a1v[m][(kb - KB0) < KB1 ? (kb - KB0) : 0]);
        }
#pragma unroll
        for (int n = 0; n < 4; n++) {
            short8 bf = __builtin_bit_cast(short8, *(const uint4*)(&ldsw[(n * 16 + lrow) * KP + kb * 32 + kg * 8]));
            acc[0][n] = __builtin_amdgcn_mfma_f32_16x16x32_bf16(bf, af[0], acc[0][n], 0, 0, 0);
            acc[1][n] = __builtin_amdgcn_mfma_f32_16x16x32_bf16(bf, af[1], acc[1][n], 0, 0, 0);
        }
    }

    // ---- epilogue: packed 8B stores ----
#pragma unroll
    for (int m = 0; m < 2; m++) {
        long r = rowbase + m * 16 + lrow;
        if (r >= N_ATOMS) continue;
#pragma unroll
        for (int n = 0; n < 4; n++) {
            int c0 = nh * 64 + n * 16 + kg * 4;
            float4 b4 = *(const float4*)(bias + c0);
            float v0 = acc[m][n][0] + b4.x;
            float v1 = acc[m][n][1] + b4.y;
            float v2 = acc[m][n][2] + b4.z;
            float v3 = acc[m][n][3] + b4.w;
            if constexpr (ADDX) {
                uint2 xv = *(const uint2*)(Xadd + r * 128 + c0);
                v0 += __builtin_bit_cast(float, xv.x << 16);
                v1 += __builtin_bit_cast(float, xv.x & 0xFFFF0000u);
                v2 += __builtin_bit_cast(float, xv.y << 16);
                v3 += __builtin_bit_cast(float, xv.y & 0xFFFF0000u);
            }
            uint2 o;
            o.x = (u32)f2bf(v0) | ((u32)f2bf(v1) << 16);
            o.y = (u32)f2bf(v2) | ((u32)f2bf(v3) << 16);
            *(uint2*)(Out + r * 128 + c0) = o;
        }
    }
}

// ---------------- readout: per-mol max over 20 atoms (w/ relu) then dot ffn_w ----------
__global__ __launch_bounds__(256) void readout(const u16* __restrict__ ah,
                                               const float* __restrict__ ffn_w,
                                               const float* __restrict__ ffn_b,
                                               float* __restrict__ out) {
    int mol  = blockIdx.x * 4 + (threadIdx.x >> 6);
    int lane = threadIdx.x & 63;
    if (mol >= N_MOLS) return;
    float m0 = -1e30f, m1 = -1e30f;
    const u16* base = ah + (long)mol * APM * 128 + 2 * lane;
#pragma unroll
    for (int a = 0; a < APM; a++) {
        u32 v = *(const u32*)(base + a * 128);
        m0 = fmaxf(m0, bf2f((u16)(v & 0xFFFFu)));
        m1 = fmaxf(m1, bf2f((u16)(v >> 16)));
    }
    m0 = fmaxf(m0, 0.f);  // relu commutes with max
    m1 = fmaxf(m1, 0.f);
    float p = m0 * ffn_w[2 * lane] + m1 * ffn_w[2 * lane + 1];
#pragma unroll
    for (int off = 32; off > 0; off >>= 1) p += __shfl_down(p, off);
    if (lane == 0) out[mol] = p + ffn_b[0];
}

extern "C" void kernel_launch(void* const* d_in, const int* in_sizes, int n_in,
                              void* d_out, int out_size, void* d_ws, size_t ws_size,
                              hipStream_t stream) {
    const float* f_atoms = (const float*)d_in[0];
    const float* f_bonds = (const float*)d_in[1];
    const float* Wi_w = (const float*)d_in[2];
    const float* Wi_b = (const float*)d_in[3];
    const float* Wh_w = (const float*)d_in[4];
    const float* Wh_b = (const float*)d_in[5];
    const float* Wo_w = (const float*)d_in[6];
    const float* Wo_b = (const float*)d_in[7];
    const float* ffn_w = (const float*)d_in[8];
    const float* ffn_b = (const float*)d_in[9];
    const int* a2a = (const int*)d_in[10];
    const int* a2b = (const int*)d_in[11];
    float* out = (float*)d_out;

    char* ws = (char*)d_ws;
    u16* fa    = (u16*)(ws);                  // 160,000,000
    u16* xb    = (u16*)(ws + 160000000L);     // 128,000,000  (pre-relu x)
    u16* msgA  = (u16*)(ws + 288000000L);     // 128,000,000
    u16* msgB  = (u16*)(ws + 416000000L);     // 128,000,000
    u16* nsum  = (u16*)(ws + 544000000L);     // 128,000,000  (gathered relu-sum)
    u16* nbond = (u16*)(ws + 672000000L);     // 32,000,000
    u16* Wip   = (u16*)(ws + 704000000L);
    u16* Whp   = (u16*)(ws + 704040960L);
    u16* Wop   = (u16*)(ws + 704081920L);

    prep_weights<<<64, 256, 0, stream>>>(Wi_w, Wh_w, Wo_w, Wip, Whp, Wop);
    fa_convert<<<(N_ATOMS + CROWS - 1) / CROWS, 256, 0, stream>>>(f_atoms, fa);
    bond_gather<<<31250, 256, 0, stream>>>(f_bonds, a2b, nbond);

    // x = f_atoms @ Wi^T + b  (pre-relu)
    gemm_mp<5, 0, false><<<7814, 256, 0, stream>>>(
        fa, 160, (const u16*)nullptr, 0, Wip, Wi_b, (const u16*)nullptr, xb);

    // depth 1
    gather_relu_sum<<<31250, 256, 0, stream>>>(xb, a2a, nsum);
    gemm_mp<4, 1, true><<<7814, 256, 0, stream>>>(
        nsum, 128, nbond, 32, Whp, Wh_b, xb, msgA);
    // depth 2
    gather_relu_sum<<<31250, 256, 0, stream>>>(msgA, a2a, nsum);
    gemm_mp<4, 1, true><<<7814, 256, 0, stream>>>(
        nsum, 128, nbond, 32, Whp, Wh_b, xb, msgB);
    // final: [fa | gather(relu(msgB))] @ Wo^T -> atom_hiddens (pre-relu) into msgA
    gather_relu_sum<<<31250, 256, 0, stream>>>(msgB, a2a, nsum);
    gemm_mp<5, 4, false><<<7814, 256, 0, stream>>>(
        fa, 160, nsum, 128, Wop, Wo_b, (const u16*)nullptr, msgA);

    readout<<<6250, 256, 0, stream>>>(msgA, ffn_w, ffn_b, out);
}

// Round 6
// 885.246 us; speedup vs baseline: 1.1496x; 1.1496x over previous
//
#include <hip/hip_runtime.h>
#include <hip/hip_bf16.h>

#define N_ATOMS   500000
#define N_BONDS   1000000
#define MAX_NB    6
#define ATOM_FDIM 133
#define BOND_FDIM 14
#define HIDDEN    128
#define N_MOLS    25000
#define APM       20

typedef __attribute__((ext_vector_type(8))) short short8;
typedef __attribute__((ext_vector_type(4))) float f32x4;
typedef unsigned short u16;
typedef unsigned int   u32;

__device__ __forceinline__ float bf2f(u16 u) {
    u32 t = ((u32)u) << 16;
    return __builtin_bit_cast(float, t);
}
__device__ __forceinline__ u16 f2bf(float f) {
    u32 t = __builtin_bit_cast(u32, f);
    t += 0x7FFFu + ((t >> 16) & 1u);
    return (u16)(t >> 16);
}

// async global->LDS, 16B per lane. HW writes lane i at (uniform lds base) + i*16.
__device__ __forceinline__ void gl16(const u16* g, u16* l) {
    __builtin_amdgcn_global_load_lds(
        (__attribute__((address_space(1))) void*)(g),
        (__attribute__((address_space(3))) void*)(l), 16, 0, 0);
}

// ---------------- weight prep: fp32 -> padded bf16 ----------------
__global__ void prep_weights(const float* __restrict__ Wi, const float* __restrict__ Wh,
                             const float* __restrict__ Wo,
                             u16* __restrict__ Wip, u16* __restrict__ Whp, u16* __restrict__ Wop) {
    int stride = gridDim.x * blockDim.x;
    int tid = blockIdx.x * blockDim.x + threadIdx.x;
    for (int i = tid; i < 128 * 160; i += stride) {
        int r = i / 160, c = i % 160;
        Wip[i] = (c < 133) ? f2bf(Wi[r * 133 + c]) : (u16)0;
        Whp[i] = (c < 142) ? f2bf(Wh[r * 142 + c]) : (u16)0;
    }
    for (int i = tid; i < 128 * 288; i += stride) {
        int r = i / 288, c = i % 288;
        float v = 0.f;
        if (c < 133)      v = Wo[r * 261 + c];
        else if (c >= 160) v = Wo[r * 261 + (c - 27)];
        Wop[i] = f2bf(v);
    }
}

// ---------------- f_atoms fp32 [N][133] -> bf16 [N][160], LDS-staged ----------------
#define CROWS 24
__global__ __launch_bounds__(256) void fa_convert(const float* __restrict__ fa, u16* __restrict__ out) {
    __shared__ float buf[CROWS * 133];
    const long row0 = (long)blockIdx.x * CROWS;
    const int rows = (int)((N_ATOMS - row0) < CROWS ? (N_ATOMS - row0) : CROWS);
    const float* src = fa + row0 * ATOM_FDIM;
    if (rows == CROWS) {
        for (int i = threadIdx.x; i < (CROWS * 133) / 4; i += 256)
            *(float4*)(&buf[i * 4]) = *(const float4*)(src + i * 4);
    } else {
        for (int i = threadIdx.x; i < rows * 133; i += 256) buf[i] = src[i];
    }
    __syncthreads();
    for (int j = threadIdx.x; j < rows * 20; j += 256) {
        int r = j / 20, c8 = (j % 20) * 8;
        u16 u[8];
#pragma unroll
        for (int e = 0; e < 8; e++) {
            int c = c8 + e;
            u[e] = (c < ATOM_FDIM) ? f2bf(buf[r * 133 + c]) : (u16)0;
        }
        uint4 v;
        v.x = (u32)u[0] | ((u32)u[1] << 16);
        v.y = (u32)u[2] | ((u32)u[3] << 16);
        v.z = (u32)u[4] | ((u32)u[5] << 16);
        v.w = (u32)u[6] | ((u32)u[7] << 16);
        *(uint4*)(out + (row0 + r) * 160 + c8) = v;
    }
}

// ---------------- bond pre-sum: sum_j f_bonds[a2b[:,j]] -> bf16 [N][32] ----------------
__global__ __launch_bounds__(256) void bond_gather(const float* __restrict__ fb, const int* __restrict__ a2b,
                                                   u16* __restrict__ outp) {
    long t = (long)blockIdx.x * 256 + threadIdx.x;
    int atom = (int)(t >> 4);
    int c2   = (int)(t & 15);
    if (atom >= N_ATOMS) return;
    int c0 = 2 * c2, c1 = c0 + 1;
    float s0 = 0.f, s1 = 0.f;
    if (c0 < BOND_FDIM) {
#pragma unroll
        for (int j = 0; j < MAX_NB; j++) {
            int idx = a2b[atom * 6 + j];
            const float* row = fb + (long)idx * BOND_FDIM;
            s0 += row[c0];
            if (c1 < BOND_FDIM) s1 += row[c1];
        }
    }
    *(u32*)(outp + (long)atom * 32 + c0) = (u32)f2bf(s0) | ((u32)f2bf(s1) << 16);
}

// ---------------- gather-relu-sum: dst[a] = sum_j relu(src[a2a[a,j]]) (bf16 128-wide) ---
__global__ __launch_bounds__(256) void gather_relu_sum(const u16* __restrict__ src,
                                                       const int* __restrict__ a2a,
                                                       u16* __restrict__ dst) {
    long t = (long)blockIdx.x * 256 + threadIdx.x;
    int atom = (int)(t >> 4);
    int c8   = (int)(t & 15) << 3;
    float s[8] = {0, 0, 0, 0, 0, 0, 0, 0};
#pragma unroll
    for (int j = 0; j < MAX_NB; j++) {
        int idx = a2a[atom * 6 + j];
        uint4 v = *(const uint4*)(src + (long)idx * 128 + c8);
        u32 w[4] = {v.x, v.y, v.z, v.w};
#pragma unroll
        for (int q = 0; q < 4; q++) {
            s[2 * q]     += fmaxf(__builtin_bit_cast(float, w[q] << 16), 0.f);
            s[2 * q + 1] += fmaxf(__builtin_bit_cast(float, w[q] & 0xFFFF0000u), 0.f);
        }
    }
    uint4 o;
    o.x = (u32)f2bf(s[0]) | ((u32)f2bf(s[1]) << 16);
    o.y = (u32)f2bf(s[2]) | ((u32)f2bf(s[3]) << 16);
    o.z = (u32)f2bf(s[4]) | ((u32)f2bf(s[5]) << 16);
    o.w = (u32)f2bf(s[6]) | ((u32)f2bf(s[7]) << 16);
    *(uint4*)(dst + (long)atom * 128 + c8) = o;
}

// ---------------- persistent async GEMM ----------------
// Out[N][128] = concat(A0,A1)[N][32*KB] @ Wp^T + bias (+Xadd), swapped-operand MFMA.
// - W fragments staged ONCE per block into LDS, fragment-linear [slot][lane*16B]
//   -> all ds_reads are lane*16 (conflict-free), staging amortized over ~30 tiles.
// - A (and Xadd) tiles staged via global_load_lds (async DMA, no VGPRs), double
//   buffered; counted s_waitcnt vmcnt(KB+X) keeps next tile's DMAs in flight (T4).
// - Per-wave private A/X slots -> ZERO barriers in the main loop.
template <int KB0, int KB1, bool ADDX, int WAVES>
__global__ __launch_bounds__(WAVES * 64, 2) void gemm_pp(
    const u16* __restrict__ A0, int ldA0,
    const u16* __restrict__ A1, int ldA1,
    const u16* __restrict__ Wp, const float* __restrict__ bias,
    const u16* __restrict__ Xadd, u16* __restrict__ Out) {
    constexpr int KB   = KB0 + KB1;
    constexpr int KP   = KB * 32;
    constexpr int TILE = WAVES * 16;
    constexpr long NT  = (N_ATOMS + TILE - 1) / TILE;
    constexpr int WSLOTS = KB * 8;
    constexpr int ASLOTS = 2 * WAVES * KB;
    constexpr int XSLOTS = ADDX ? 2 * WAVES * 4 : 0;
    constexpr int NVM  = KB + (ADDX ? 4 : 0);  // DMAs per wave per stage
    __shared__ __align__(16) u16 lds[(WSLOTS + ASLOTS + XSLOTS) * 512];

    const int lane = threadIdx.x & 63;
    const int wave = threadIdx.x >> 6;
    const int lrow = lane & 15;
    const int kg   = lane >> 4;

    u16* WL = lds;
    u16* AL = lds + WSLOTS * 512;
    u16* XL = lds + (WSLOTS + ASLOTS) * 512;

    // ---- stage all W fragments once (distributed across waves) ----
    for (int s = wave; s < WSLOTS; s += WAVES) {
        int kb = s >> 3, n = s & 7;
        gl16(Wp + (n * 16 + lrow) * KP + kb * 32 + kg * 8, WL + s * 512);
    }
    asm volatile("s_waitcnt vmcnt(0)" ::: "memory");
    __syncthreads();

    float4 b4[8];
#pragma unroll
    for (int n = 0; n < 8; n++) b4[n] = *(const float4*)(bias + n * 16 + kg * 4);

    const int G = gridDim.x;

    auto stage = [&](int buf, long t) {
        long row0w = t * TILE + wave * 16;
        long r = row0w + lrow;
        if (r >= N_ATOMS) r = N_ATOMS - 1;  // dup-row reads are safe; stores guarded
        u16* ab = AL + (buf * WAVES + wave) * KB * 512;
        if constexpr (KB0 > 0) {
            const u16* p = A0 + r * ldA0 + kg * 8;
#pragma unroll
            for (int kb = 0; kb < KB0; kb++) gl16(p + kb * 32, ab + kb * 512);
        }
        if constexpr (KB1 > 0) {
            const u16* p = A1 + r * ldA1 + kg * 8;
#pragma unroll
            for (int kb = 0; kb < KB1; kb++) gl16(p + kb * 32, ab + (KB0 + kb) * 512);
        }
        if constexpr (ADDX) {
            u16* xbse = XL + (buf * WAVES + wave) * 4 * 512;
#pragma unroll
            for (int j = 0; j < 4; j++) {
                long rx = row0w + j * 4 + (lane >> 4);
                if (rx >= N_ATOMS) rx = N_ATOMS - 1;
                gl16(Xadd + rx * 128 + (lane & 15) * 8, xbse + j * 512);
            }
        }
    };

    int buf = 0;
    long t0 = blockIdx.x;
    stage(0, t0);
    for (long t = t0; t < NT; t += G) {
        long tn = (t + G < NT) ? (t + G) : t;
        stage(buf ^ 1, tn);
        asm volatile("s_waitcnt vmcnt(%0)" :: "n"(NVM) : "memory");
        __builtin_amdgcn_sched_barrier(0);

        const u16* abase = AL + (buf * WAVES + wave) * KB * 512;
        f32x4 acc[8];
#pragma unroll
        for (int n = 0; n < 8; n++) acc[n] = (f32x4){0.f, 0.f, 0.f, 0.f};
#pragma unroll
        for (int kb = 0; kb < KB; kb++) {
            short8 af = *(const short8*)(abase + kb * 512 + lane * 8);
#pragma unroll
            for (int n = 0; n < 8; n++) {
                short8 bf = *(const short8*)(WL + (kb * 8 + n) * 512 + lane * 8);
                acc[n] = __builtin_amdgcn_mfma_f32_16x16x32_bf16(bf, af, acc[n], 0, 0, 0);
            }
        }

        long r = t * TILE + wave * 16 + lrow;
        if (r < N_ATOMS) {
            const u16* xbse = XL + (buf * WAVES + wave) * 4 * 512 +
                              (lrow >> 2) * 512 + (lrow & 3) * 128 + (kg >> 1) * 8 + (kg & 1) * 4;
#pragma unroll
            for (int n = 0; n < 8; n++) {
                float v0 = acc[n][0] + b4[n].x;
                float v1 = acc[n][1] + b4[n].y;
                float v2 = acc[n][2] + b4[n].z;
                float v3 = acc[n][3] + b4[n].w;
                if constexpr (ADDX) {
                    uint2 xr = *(const uint2*)(xbse + n * 16);
                    v0 += __builtin_bit_cast(float, xr.x << 16);
                    v1 += __builtin_bit_cast(float, xr.x & 0xFFFF0000u);
                    v2 += __builtin_bit_cast(float, xr.y << 16);
                    v3 += __builtin_bit_cast(float, xr.y & 0xFFFF0000u);
                }
                uint2 o;
                o.x = (u32)f2bf(v0) | ((u32)f2bf(v1) << 16);
                o.y = (u32)f2bf(v2) | ((u32)f2bf(v3) << 16);
                *(uint2*)(Out + r * 128 + n * 16 + kg * 4) = o;
            }
        }
        buf ^= 1;
    }
}

// ---------------- readout: per-mol max over 20 atoms (w/ relu) then dot ffn_w ----------
__global__ __launch_bounds__(256) void readout(const u16* __restrict__ ah,
                                               const float* __restrict__ ffn_w,
                                               const float* __restrict__ ffn_b,
                                               float* __restrict__ out) {
    int mol  = blockIdx.x * 4 + (threadIdx.x >> 6);
    int lane = threadIdx.x & 63;
    if (mol >= N_MOLS) return;
    float m0 = -1e30f, m1 = -1e30f;
    const u16* base = ah + (long)mol * APM * 128 + 2 * lane;
#pragma unroll
    for (int a = 0; a < APM; a++) {
        u32 v = *(const u32*)(base + a * 128);
        m0 = fmaxf(m0, bf2f((u16)(v & 0xFFFFu)));
        m1 = fmaxf(m1, bf2f((u16)(v >> 16)));
    }
    m0 = fmaxf(m0, 0.f);  // relu commutes with max
    m1 = fmaxf(m1, 0.f);
    float p = m0 * ffn_w[2 * lane] + m1 * ffn_w[2 * lane + 1];
#pragma unroll
    for (int off = 32; off > 0; off >>= 1) p += __shfl_down(p, off);
    if (lane == 0) out[mol] = p + ffn_b[0];
}

extern "C" void kernel_launch(void* const* d_in, const int* in_sizes, int n_in,
                              void* d_out, int out_size, void* d_ws, size_t ws_size,
                              hipStream_t stream) {
    const float* f_atoms = (const float*)d_in[0];
    const float* f_bonds = (const float*)d_in[1];
    const float* Wi_w = (const float*)d_in[2];
    const float* Wi_b = (const float*)d_in[3];
    const float* Wh_w = (const float*)d_in[4];
    const float* Wh_b = (const float*)d_in[5];
    const float* Wo_w = (const float*)d_in[6];
    const float* Wo_b = (const float*)d_in[7];
    const float* ffn_w = (const float*)d_in[8];
    const float* ffn_b = (const float*)d_in[9];
    const int* a2a = (const int*)d_in[10];
    const int* a2b = (const int*)d_in[11];
    float* out = (float*)d_out;

    char* ws = (char*)d_ws;
    u16* fa    = (u16*)(ws);                  // 160,000,000
    u16* xb    = (u16*)(ws + 160000000L);     // 128,000,000  (pre-relu x)
    u16* msgA  = (u16*)(ws + 288000000L);     // 128,000,000
    u16* msgB  = (u16*)(ws + 416000000L);     // 128,000,000
    u16* nsum  = (u16*)(ws + 544000000L);     // 128,000,000  (gathered relu-sum)
    u16* nbond = (u16*)(ws + 672000000L);     // 32,000,000
    u16* Wip   = (u16*)(ws + 704000000L);
    u16* Whp   = (u16*)(ws + 704040960L);
    u16* Wop   = (u16*)(ws + 704081920L);

    prep_weights<<<64, 256, 0, stream>>>(Wi_w, Wh_w, Wo_w, Wip, Whp, Wop);
    fa_convert<<<(N_ATOMS + CROWS - 1) / CROWS, 256, 0, stream>>>(f_atoms, fa);
    bond_gather<<<31250, 256, 0, stream>>>(f_bonds, a2b, nbond);

    // x = f_atoms @ Wi^T + b (pre-relu). LDS 80KB -> 2 blocks/CU, grid 512.
    gemm_pp<5, 0, false, 4><<<512, 256, 0, stream>>>(
        fa, 160, (const u16*)nullptr, 0, Wip, Wi_b, (const u16*)nullptr, xb);

    // depth 1
    gather_relu_sum<<<31250, 256, 0, stream>>>(xb, a2a, nsum);
    gemm_pp<4, 1, true, 4><<<256, 256, 0, stream>>>(
        nsum, 128, nbond, 32, Whp, Wh_b, xb, msgA);
    // depth 2
    gather_relu_sum<<<31250, 256, 0, stream>>>(msgA, a2a, nsum);
    gemm_pp<4, 1, true, 4><<<256, 256, 0, stream>>>(
        nsum, 128, nbond, 32, Whp, Wh_b, xb, msgB);
    // final: [fa | gather(relu(msgB))] @ Wo^T -> atom_hiddens (pre-relu) into msgA
    // KB=9: 3 waves/48-row tiles keeps LDS at 126KB.
    gather_relu_sum<<<31250, 256, 0, stream>>>(msgB, a2a, nsum);
    gemm_pp<5, 4, false, 3><<<256, 192, 0, stream>>>(
        fa, 160, nsum, 128, Wop, Wo_b, (const u16*)nullptr, msgA);

    readout<<<6250, 256, 0, stream>>>(msgA, ffn_w, ffn_b, out);
}